// Round 4
// baseline (10110.880 us; speedup 1.0000x reference)
//
#include <hip/hip_runtime.h>
#include <hip/hip_bf16.h>
#include <stdint.h>

// 2-layer LSTM, B=1024 T=80 E=100 U=512, bf16 MFMA path.
// R1: layer2(t-1) || layer1(t) software pipeline.
// R2: XCD-colocating tile swizzle (g%8 -> blockIdx%8).
// R3: K-loop depth-3 prefetch, 4-buffer LDS ring, counted vmcnt.
// R4: 128x128 output tile; halved staged bytes -> 2428->1778us (bytes-bound confirmed).
// R5: PERSISTENT kernel — all 81 pipeline steps inside one launch with a hand-rolled
//     grid barrier (monotonic counter, device-scope atomics, __threadfence for cross-XCD
//     visibility). C cell-state moves to 8 registers/thread (block<->slice mapping is
//     now fixed for the whole sequence): removes 16 MB/step of fp32 C traffic, all
//     launch gaps, and keeps each XCD's ~0.8 MB weight slice L2-resident.
//     Residency is capacity-guaranteed: 256 blocks, 64KB LDS + <=256 VGPR
//     (__launch_bounds__(512,2)) -> >=256 co-resident slots. No cooperative API.

#define B_ 1024
#define T_ 80
#define NBLK 256

using bf16 = __hip_bfloat16;
typedef __attribute__((ext_vector_type(8))) short short8;
typedef __attribute__((ext_vector_type(4))) float f32x4;
typedef __attribute__((ext_vector_type(4))) unsigned short ushort4v;

__device__ __forceinline__ float sigf(float x) { return 1.f / (1.f + __expf(-x)); }
__device__ __forceinline__ float tanh_f(float x) { return 2.f / (1.f + __expf(-2.f * x)) - 1.f; }

typedef const __attribute__((address_space(1))) void* gp1_t;
typedef __attribute__((address_space(3))) void* lp3_t;
__device__ __forceinline__ void llds16(const void* g, void* l) {
  __builtin_amdgcn_global_load_lds((gp1_t)g, (lp3_t)l, 16, 0, 0);
}

// grid barrier: monotonic counter, no reset -> no ABA. All threads call; tid0 spins.
__device__ __forceinline__ void grid_barrier(unsigned* cnt, unsigned target) {
  __threadfence();   // release: drain this thread's stores, L2 writeback (agent scope)
  __syncthreads();
  if (threadIdx.x == 0) {
    __hip_atomic_fetch_add(cnt, 1u, __ATOMIC_ACQ_REL, __HIP_MEMORY_SCOPE_AGENT);
    while (__hip_atomic_load(cnt, __ATOMIC_ACQUIRE, __HIP_MEMORY_SCOPE_AGENT) < target)
      __builtin_amdgcn_s_sleep(2);
  }
  __syncthreads();
  __threadfence();   // acquire: invalidate stale lines before reading peers' H
}

// XP[t][b][e] (e padded to 128 with zeros), bf16
__global__ void embed_kernel(const int* __restrict__ tokens, const float* __restrict__ emb,
                             bf16* __restrict__ XP) {
  int idx = blockIdx.x * 256 + threadIdx.x;  // over T_*B_*128
  int e = idx & 127;
  int bt = idx >> 7;
  int b = bt & (B_ - 1);
  int t = bt >> 10;
  if (t >= T_) return;
  int tok = tokens[b * T_ + t];
  float v = (e < 100) ? emb[tok * 100 + e] : 0.f;
  XP[idx] = __float2bfloat16(v);
}

// W [Kreal][2048] fp32 -> WT [2048][Kp] bf16, coalesced both ways via 32x32 LDS tile
__global__ void transpose_kernel(const float* __restrict__ W, bf16* __restrict__ WT,
                                 int Kreal, int Kp) {
  __shared__ float tile[32][33];
  int tn = blockIdx.x * 32;
  int tk = blockIdx.y * 32;
  int lx = threadIdx.x & 31;
  int ly = threadIdx.x >> 5;  // 8
#pragma unroll
  for (int r = ly; r < 32; r += 8) {
    int k = tk + r;
    tile[r][lx] = (k < Kreal) ? W[(size_t)k * 2048 + tn + lx] : 0.f;
  }
  __syncthreads();
#pragma unroll
  for (int r = ly; r < 32; r += 8) {
    WT[(size_t)(tn + r) * Kp + tk + lx] = __float2bfloat16(tile[lx][r]);
  }
}

// Persistent dual-role cell kernel. Blocks 0..127: layer1 (t=it, it<T_);
// blocks 128..255: layer2 (t=it-1, it>=1). Grid barrier between iterations.
// Block tile 128 rows x 32 units; 8 waves (2m x 4n); wave = 4x2 16x16x32 frags.
// LDS: 4 x 16KB staging ring; epilogue reuses as 64x133 f32 z-tile (2 passes).
// C cell-state: creg[pass][4] per thread (fp32, bit-identical to old global C path).
__global__ __launch_bounds__(512, 2) void lstm_persist(
    const bf16* __restrict__ XP, const bf16* __restrict__ W1T, const bf16* __restrict__ U1T,
    const bf16* __restrict__ W2T, const bf16* __restrict__ U2T,
    const float* __restrict__ b1, const float* __restrict__ b2,
    bf16* __restrict__ H1, bf16* __restrict__ H2, unsigned* bar) {
  __shared__ alignas(16) char smem[65536];
  const int role = blockIdx.x >> 7;  // 0 = layer1, 1 = layer2
  const int lb = blockIdx.x & 127;
  const int g = (lb & 7) | ((lb >> 6) << 3);  // unit-group 0..15 (XCD-colocated)
  const int bm = (lb >> 3) & 7;               // 128-row tile
  const int u0 = g * 32;
  const int tid = threadIdx.x;
  const int w = tid >> 6, l = tid & 63, q = l >> 4, m = l & 15;
  const int wm = w >> 2, wn = w & 3;

  const bf16* B0 = role ? W2T : W1T;
  const bf16* B1 = role ? U2T : U1T;
  const int ldb0 = role ? 512 : 128;
  const int lda0 = role ? 512 : 128;
  const int nkt0 = role ? 16 : 4;
  const int total = nkt0 + 16;
  const float* bias = role ? b2 : b1;

  // B staging rows fixed for the whole sequence
  const int brow_n = (w >> 1) * 512 + u0 + (w & 1) * 16 + m;
  const bf16* brow0 = B0 + (size_t)brow_n * ldb0;
  const bf16* brow1 = B1 + (size_t)brow_n * 512;
  const int arow_r = bm * 128 + w * 16 + m;  // A row this wave stages
  const int fbase = q * 256 + m * 16;

  // epilogue constants + persistent cell state
  const int erow = tid >> 3;     // 0..63
  const int ub = (tid & 7) * 4;  // unit within group
  float bi[4], bff[4], bg[4], bo[4];
#pragma unroll
  for (int j = 0; j < 4; ++j) {
    int gu = u0 + ub + j;
    bi[j] = bias[gu];
    bff[j] = bias[512 + gu];
    bg[j] = bias[1024 + gu];
    bo[j] = bias[1536 + gu];
  }
  float creg[2][4] = {{0.f, 0.f, 0.f, 0.f}, {0.f, 0.f, 0.f, 0.f}};

  for (int it = 0; it <= T_; ++it) {
    const bool active = role ? (it >= 1) : (it < T_);
    if (active) {
      const int t = role ? it - 1 : it;
      const bf16* A0 = role ? (H1 + (size_t)((t + 1) & 1) * 524288)
                            : (XP + (size_t)t * 131072);
      const bf16* A1 = role ? (H2 + (size_t)(t & 1) * 524288)
                            : (H1 + (size_t)(t & 1) * 524288);
      bf16* Hout = role ? (H2 + (size_t)((t + 1) & 1) * 524288)
                        : (H1 + (size_t)((t + 1) & 1) * 524288);
      const bf16* arow0 = A0 + (size_t)arow_r * lda0;
      const bf16* arow1 = A1 + (size_t)arow_r * 512;

      auto stage = [&](int kt, int buf) {
        const bf16 *ga, *gb;
        if (kt < nkt0) { int k0 = kt * 32 + q * 8; ga = arow0 + k0; gb = brow0 + k0; }
        else { int k0 = (kt - nkt0) * 32 + q * 8; ga = arow1 + k0; gb = brow1 + k0; }
        char* base = smem + buf * 16384 + w * 1024;
        llds16(ga, base);          // A
        llds16(gb, base + 8192);   // B
      };

      f32x4 acc[4][2];
#pragma unroll
      for (int mi = 0; mi < 4; ++mi)
#pragma unroll
        for (int nj = 0; nj < 2; ++nj) acc[mi][nj] = (f32x4){0.f, 0.f, 0.f, 0.f};

      stage(0, 0);
      stage(1, 1);
      stage(2, 2);
      for (int kt = 0; kt < total; ++kt) {
        const int rem = total - 1 - kt;
        if (rem >= 2)      asm volatile("s_waitcnt vmcnt(4)" ::: "memory");
        else if (rem == 1) asm volatile("s_waitcnt vmcnt(2)" ::: "memory");
        else               asm volatile("s_waitcnt vmcnt(0)" ::: "memory");
        __builtin_amdgcn_s_barrier();
        if (kt + 3 < total) stage(kt + 3, (kt + 3) & 3);
        const int cb = (kt & 3) * 16384;
        short8 a[4], b[2];
#pragma unroll
        for (int mi = 0; mi < 4; ++mi)
          a[mi] = *(const short8*)(smem + cb + (wm * 4 + mi) * 1024 + fbase);
#pragma unroll
        for (int nj = 0; nj < 2; ++nj)
          b[nj] = *(const short8*)(smem + cb + 8192 + (wn * 2 + nj) * 1024 + fbase);
#pragma unroll
        for (int mi = 0; mi < 4; ++mi)
#pragma unroll
          for (int nj = 0; nj < 2; ++nj)
            acc[mi][nj] = __builtin_amdgcn_mfma_f32_16x16x32_bf16(a[mi], b[nj], acc[mi][nj], 0, 0, 0);
      }

      __syncthreads();
      float* zs = (float*)smem;  // [64][133]
#pragma unroll
      for (int pass = 0; pass < 2; ++pass) {
        if (pass) __syncthreads();
        if (wm == pass) {
#pragma unroll
          for (int mi = 0; mi < 4; ++mi)
#pragma unroll
            for (int nj = 0; nj < 2; ++nj)
#pragma unroll
              for (int r = 0; r < 4; ++r)
                zs[(mi * 16 + q * 4 + r) * 133 + wn * 32 + nj * 16 + m] = acc[mi][nj][r];
        }
        __syncthreads();
        int grow = bm * 128 + pass * 64 + erow;
        size_t gi = (size_t)grow * 512 + u0 + ub;
        unsigned short hv[4];
#pragma unroll
        for (int j = 0; j < 4; ++j) {
          float zi = zs[erow * 133 + ub + j] + bi[j];
          float zf = zs[erow * 133 + 32 + ub + j] + bff[j];
          float zg = zs[erow * 133 + 64 + ub + j] + bg[j];
          float zo = zs[erow * 133 + 96 + ub + j] + bo[j];
          float c = sigf(zf) * creg[pass][j] + sigf(zi) * tanh_f(zg);
          float h = sigf(zo) * tanh_f(c);
          creg[pass][j] = c;
          bf16 hb = __float2bfloat16(h);
          hv[j] = *(unsigned short*)&hb;
        }
        *(ushort4v*)(Hout + gi) = (ushort4v){hv[0], hv[1], hv[2], hv[3]};
      }
    }
    grid_barrier(bar, (unsigned)(NBLK * (it + 1)));
  }
}

// out[b] = sigmoid(h2[b,:] @ Wout + bout); one wave per row
__global__ void output_kernel(const bf16* __restrict__ H2, const float* __restrict__ Wout,
                              const float* __restrict__ bout, float* __restrict__ out) {
  int w = threadIdx.x >> 6, l = threadIdx.x & 63;
  int row = blockIdx.x * 4 + w;
  const bf16* h = H2 + (size_t)row * 512;
  float s = 0.f;
#pragma unroll
  for (int k = 0; k < 8; ++k) {
    int kk = l + k * 64;
    s += __bfloat162float(h[kk]) * Wout[kk];
  }
#pragma unroll
  for (int off = 32; off > 0; off >>= 1) s += __shfl_down(s, off);
  if (l == 0) out[row] = sigf(s + bout[0]);
}

extern "C" void kernel_launch(void* const* d_in, const int* in_sizes, int n_in,
                              void* d_out, int out_size, void* d_ws, size_t ws_size,
                              hipStream_t stream) {
  const int* tokens = (const int*)d_in[0];
  const float* emb = (const float*)d_in[1];
  const float* W1 = (const float*)d_in[2];
  const float* U1 = (const float*)d_in[3];
  const float* b1 = (const float*)d_in[4];
  const float* W2 = (const float*)d_in[5];
  const float* U2 = (const float*)d_in[6];
  const float* b2 = (const float*)d_in[7];
  const float* Wout = (const float*)d_in[8];
  const float* bout = (const float*)d_in[9];
  float* out = (float*)d_out;
  char* ws = (char*)d_ws;

  const size_t oXP = 0;          // 80*1024*128 bf16 = 20971520
  const size_t oW1T = 20971520;  // 2048*128 bf16
  const size_t oU1T = 21495808;  // 2048*512 bf16
  const size_t oW2T = 23592960;
  const size_t oU2T = 25690112;
  const size_t oH1 = 27787264;   // 2 x 1024*512 bf16
  const size_t oH2 = 29884416;
  const size_t oBar = 31981568;  // barrier counter (64B)
  if (ws_size < 36175872) return;

  bf16* XP = (bf16*)(ws + oXP);
  bf16* W1T = (bf16*)(ws + oW1T);
  bf16* U1T = (bf16*)(ws + oU1T);
  bf16* W2T = (bf16*)(ws + oW2T);
  bf16* U2T = (bf16*)(ws + oU2T);
  bf16* H1 = (bf16*)(ws + oH1);
  bf16* H2 = (bf16*)(ws + oH2);
  unsigned* bar = (unsigned*)(ws + oBar);

  hipMemsetAsync(ws + oH1, 0, 1048576, stream);  // H1 buf0
  hipMemsetAsync(ws + oH2, 0, 1048576, stream);  // H2 buf0
  hipMemsetAsync(ws + oBar, 0, 64, stream);      // barrier counter

  embed_kernel<<<40960, 256, 0, stream>>>(tokens, emb, XP);
  transpose_kernel<<<dim3(64, 4), 256, 0, stream>>>(W1, W1T, 100, 128);
  transpose_kernel<<<dim3(64, 16), 256, 0, stream>>>(U1, U1T, 512, 512);
  transpose_kernel<<<dim3(64, 16), 256, 0, stream>>>(W2, W2T, 512, 512);
  transpose_kernel<<<dim3(64, 16), 256, 0, stream>>>(U2, U2T, 512, 512);

  lstm_persist<<<NBLK, 512, 0, stream>>>(XP, W1T, U1T, W2T, U2T, b1, b2, H1, H2, bar);

  // final h2 in buffer (T_&1)==0
  output_kernel<<<256, 256, 0, stream>>>(H2, Wout, bout, out);
}

// Round 5
// 2010.943 us; speedup vs baseline: 5.0279x; 5.0279x over previous
//
#include <hip/hip_runtime.h>
#include <hip/hip_bf16.h>
#include <stdint.h>

// 2-layer LSTM, B=1024 T=80 E=100 U=512, bf16 MFMA path.
// R1: layer2(t-1) || layer1(t) software pipeline.
// R2: XCD-colocating tile swizzle (g%8 -> blockIdx%8).
// R3: K-loop depth-3 prefetch, 4-buffer LDS ring, counted vmcnt.
// R4: 128x128 output tile; halved staged bytes -> 2428->1778us (bytes-bound confirmed).
// R5: persistent kernel + grid barrier. REGRESSED 10ms: acquire-spin emitted
//     buffer_inv per poll -> continuous full L2 invalidation (FETCH 777MB, 20GB/s).
// R6: fence-free persistence. Cross-block data (H1/H2) bypasses L1/L2 entirely:
//     stores = 64-bit relaxed agent-scope atomics (execute at L3, the device
//     coherence point); loads = global_load_lds aux=17 (sc0|sc1 -> read L3 direct).
//     Barrier is vmcnt(0) release + RELAXED monotonic counter + RELAXED spin --
//     zero cache-maintenance instructions, so weights stay L2-resident for all
//     81 steps. C cell-state lives in 8 registers/thread. No cooperative API;
//     residency capacity-guaranteed (256 blocks, 64KB LDS, 2 blocks/CU slots).

#define B_ 1024
#define T_ 80
#define NBLK 256

using bf16 = __hip_bfloat16;
typedef __attribute__((ext_vector_type(8))) short short8;
typedef __attribute__((ext_vector_type(4))) float f32x4;

__device__ __forceinline__ float sigf(float x) { return 1.f / (1.f + __expf(-x)); }
__device__ __forceinline__ float tanh_f(float x) { return 2.f / (1.f + __expf(-2.f * x)) - 1.f; }

typedef const __attribute__((address_space(1))) void* gp1_t;
typedef __attribute__((address_space(3))) void* lp3_t;
// AUX is the CPol immediate: 0 = cached (L1+L2); 17 = sc0|sc1 = bypass L1+L2,
// read at device coherence point (L3) -- required for cross-XCD H freshness.
template <int AUX>
__device__ __forceinline__ void llds16(const void* g, void* l) {
  __builtin_amdgcn_global_load_lds((gp1_t)g, (lp3_t)l, 16, 0, AUX);
}

// XP[t][b][e] (e padded to 128 with zeros), bf16
__global__ void embed_kernel(const int* __restrict__ tokens, const float* __restrict__ emb,
                             bf16* __restrict__ XP) {
  int idx = blockIdx.x * 256 + threadIdx.x;  // over T_*B_*128
  int e = idx & 127;
  int bt = idx >> 7;
  int b = bt & (B_ - 1);
  int t = bt >> 10;
  if (t >= T_) return;
  int tok = tokens[b * T_ + t];
  float v = (e < 100) ? emb[tok * 100 + e] : 0.f;
  XP[idx] = __float2bfloat16(v);
}

// W [Kreal][2048] fp32 -> WT [2048][Kp] bf16, coalesced both ways via 32x32 LDS tile
__global__ void transpose_kernel(const float* __restrict__ W, bf16* __restrict__ WT,
                                 int Kreal, int Kp) {
  __shared__ float tile[32][33];
  int tn = blockIdx.x * 32;
  int tk = blockIdx.y * 32;
  int lx = threadIdx.x & 31;
  int ly = threadIdx.x >> 5;  // 8
#pragma unroll
  for (int r = ly; r < 32; r += 8) {
    int k = tk + r;
    tile[r][lx] = (k < Kreal) ? W[(size_t)k * 2048 + tn + lx] : 0.f;
  }
  __syncthreads();
#pragma unroll
  for (int r = ly; r < 32; r += 8) {
    WT[(size_t)(tn + r) * Kp + tk + lx] = __float2bfloat16(tile[lx][r]);
  }
}

// fence-free grid barrier: monotonic counter, no reset -> no ABA. All relaxed:
// no buffer_inv / buffer_wbl2 is ever emitted, so L2 contents survive.
// Release = vmcnt(0): our H stores are agent-scope (write through to L3), so
// their completion at the coherence point is what vmcnt retires.
__device__ __forceinline__ void grid_barrier(unsigned* cnt, unsigned target) {
  asm volatile("s_waitcnt vmcnt(0) lgkmcnt(0)" ::: "memory");
  __syncthreads();
  if (threadIdx.x == 0) {
    __hip_atomic_fetch_add(cnt, 1u, __ATOMIC_RELAXED, __HIP_MEMORY_SCOPE_AGENT);
    while (__hip_atomic_load(cnt, __ATOMIC_RELAXED, __HIP_MEMORY_SCOPE_AGENT) < target)
      __builtin_amdgcn_s_sleep(8);
  }
  __syncthreads();
}

// Persistent dual-role cell kernel. Blocks 0..127: layer1 (t=it, it<T_);
// blocks 128..255: layer2 (t=it-1, it>=1). Grid barrier between iterations.
// Block tile 128 rows x 32 units; 8 waves (2m x 4n); wave = 4x2 16x16x32 frags.
// LDS: 4 x 16KB staging ring; epilogue reuses as 64x133 f32 z-tile (2 passes).
// C cell-state: creg[pass][4] per thread (fp32, identical math to global C path).
__global__ __launch_bounds__(512, 2) void lstm_persist(
    const bf16* __restrict__ XP, const bf16* __restrict__ W1T, const bf16* __restrict__ U1T,
    const bf16* __restrict__ W2T, const bf16* __restrict__ U2T,
    const float* __restrict__ b1, const float* __restrict__ b2,
    bf16* __restrict__ H1, bf16* __restrict__ H2, unsigned* bar) {
  __shared__ alignas(16) char smem[65536];
  const int role = blockIdx.x >> 7;  // 0 = layer1, 1 = layer2
  const int lb = blockIdx.x & 127;
  const int g = (lb & 7) | ((lb >> 6) << 3);  // unit-group 0..15 (XCD-colocated)
  const int bm = (lb >> 3) & 7;               // 128-row tile
  const int u0 = g * 32;
  const int tid = threadIdx.x;
  const int w = tid >> 6, l = tid & 63, q = l >> 4, m = l & 15;
  const int wm = w >> 2, wn = w & 3;

  const bf16* B0 = role ? W2T : W1T;
  const bf16* B1 = role ? U2T : U1T;
  const int ldb0 = role ? 512 : 128;
  const int lda0 = role ? 512 : 128;
  const int nkt0 = role ? 16 : 4;
  const int total = nkt0 + 16;
  const float* bias = role ? b2 : b1;

  // B staging rows fixed for the whole sequence (weights: cached, L2-resident)
  const int brow_n = (w >> 1) * 512 + u0 + (w & 1) * 16 + m;
  const bf16* brow0 = B0 + (size_t)brow_n * ldb0;
  const bf16* brow1 = B1 + (size_t)brow_n * 512;
  const int arow_r = bm * 128 + w * 16 + m;  // A row this wave stages
  const int fbase = q * 256 + m * 16;

  // epilogue constants + persistent cell state
  const int erow = tid >> 3;     // 0..63
  const int ub = (tid & 7) * 4;  // unit within group
  float bi[4], bff[4], bg[4], bo[4];
#pragma unroll
  for (int j = 0; j < 4; ++j) {
    int gu = u0 + ub + j;
    bi[j] = bias[gu];
    bff[j] = bias[512 + gu];
    bg[j] = bias[1024 + gu];
    bo[j] = bias[1536 + gu];
  }
  float creg[2][4] = {{0.f, 0.f, 0.f, 0.f}, {0.f, 0.f, 0.f, 0.f}};

  for (int it = 0; it <= T_; ++it) {
    const bool active = role ? (it >= 1) : (it < T_);
    if (active) {
      const int t = role ? it - 1 : it;
      const bf16* A0 = role ? (H1 + (size_t)((t + 1) & 1) * 524288)
                            : (XP + (size_t)t * 131072);
      const bf16* A1 = role ? (H2 + (size_t)(t & 1) * 524288)
                            : (H1 + (size_t)(t & 1) * 524288);
      bf16* Hout = role ? (H2 + (size_t)((t + 1) & 1) * 524288)
                        : (H1 + (size_t)((t + 1) & 1) * 524288);
      const bf16* arow0 = A0 + (size_t)arow_r * lda0;
      const bf16* arow1 = A1 + (size_t)arow_r * 512;

      auto stage = [&](int kt, int buf) {
        char* base = smem + buf * 16384 + w * 1024;
        if (kt < nkt0) {
          int k0 = kt * 32 + q * 8;
          if (role) llds16<17>(arow0 + k0, base);  // A0 = H1 (cross-block, bypass)
          else      llds16<0>(arow0 + k0, base);   // A0 = XP (pre-written, cached)
          llds16<0>(brow0 + k0, base + 8192);      // weights: cached
        } else {
          int k0 = (kt - nkt0) * 32 + q * 8;
          llds16<17>(arow1 + k0, base);            // A1 = H1/H2 (cross-block, bypass)
          llds16<0>(brow1 + k0, base + 8192);      // weights: cached
        }
      };

      f32x4 acc[4][2];
#pragma unroll
      for (int mi = 0; mi < 4; ++mi)
#pragma unroll
        for (int nj = 0; nj < 2; ++nj) acc[mi][nj] = (f32x4){0.f, 0.f, 0.f, 0.f};

      stage(0, 0);
      stage(1, 1);
      stage(2, 2);
      for (int kt = 0; kt < total; ++kt) {
        const int rem = total - 1 - kt;
        if (rem >= 2)      asm volatile("s_waitcnt vmcnt(4)" ::: "memory");
        else if (rem == 1) asm volatile("s_waitcnt vmcnt(2)" ::: "memory");
        else               asm volatile("s_waitcnt vmcnt(0)" ::: "memory");
        __builtin_amdgcn_s_barrier();
        if (kt + 3 < total) stage(kt + 3, (kt + 3) & 3);
        const int cb = (kt & 3) * 16384;
        short8 a[4], b[2];
#pragma unroll
        for (int mi = 0; mi < 4; ++mi)
          a[mi] = *(const short8*)(smem + cb + (wm * 4 + mi) * 1024 + fbase);
#pragma unroll
        for (int nj = 0; nj < 2; ++nj)
          b[nj] = *(const short8*)(smem + cb + 8192 + (wn * 2 + nj) * 1024 + fbase);
#pragma unroll
        for (int mi = 0; mi < 4; ++mi)
#pragma unroll
          for (int nj = 0; nj < 2; ++nj)
            acc[mi][nj] = __builtin_amdgcn_mfma_f32_16x16x32_bf16(a[mi], b[nj], acc[mi][nj], 0, 0, 0);
      }

      __syncthreads();
      float* zs = (float*)smem;  // [64][133]
#pragma unroll
      for (int pass = 0; pass < 2; ++pass) {
        if (pass) __syncthreads();
        if (wm == pass) {
#pragma unroll
          for (int mi = 0; mi < 4; ++mi)
#pragma unroll
            for (int nj = 0; nj < 2; ++nj)
#pragma unroll
              for (int r = 0; r < 4; ++r)
                zs[(mi * 16 + q * 4 + r) * 133 + wn * 32 + nj * 16 + m] = acc[mi][nj][r];
        }
        __syncthreads();
        int grow = bm * 128 + pass * 64 + erow;
        size_t gi = (size_t)grow * 512 + u0 + ub;
        unsigned long long hq = 0ull;
#pragma unroll
        for (int j = 0; j < 4; ++j) {
          float zi = zs[erow * 133 + ub + j] + bi[j];
          float zf = zs[erow * 133 + 32 + ub + j] + bff[j];
          float zg = zs[erow * 133 + 64 + ub + j] + bg[j];
          float zo = zs[erow * 133 + 96 + ub + j] + bo[j];
          float c = sigf(zf) * creg[pass][j] + sigf(zi) * tanh_f(zg);
          float h = sigf(zo) * tanh_f(c);
          creg[pass][j] = c;
          bf16 hb = __float2bfloat16(h);
          hq |= (unsigned long long)(*(unsigned short*)&hb) << (16 * j);
        }
        // agent-scope store: executes at the device coherence point (L3);
        // relaxed -> no fence instructions emitted.
        __hip_atomic_store(reinterpret_cast<unsigned long long*>(Hout + gi), hq,
                           __ATOMIC_RELAXED, __HIP_MEMORY_SCOPE_AGENT);
      }
    }
    grid_barrier(bar, (unsigned)(NBLK * (it + 1)));
  }
}

// out[b] = sigmoid(h2[b,:] @ Wout + bout); one wave per row
__global__ void output_kernel(const bf16* __restrict__ H2, const float* __restrict__ Wout,
                              const float* __restrict__ bout, float* __restrict__ out) {
  int w = threadIdx.x >> 6, l = threadIdx.x & 63;
  int row = blockIdx.x * 4 + w;
  const bf16* h = H2 + (size_t)row * 512;
  float s = 0.f;
#pragma unroll
  for (int k = 0; k < 8; ++k) {
    int kk = l + k * 64;
    s += __bfloat162float(h[kk]) * Wout[kk];
  }
#pragma unroll
  for (int off = 32; off > 0; off >>= 1) s += __shfl_down(s, off);
  if (l == 0) out[row] = sigf(s + bout[0]);
}

extern "C" void kernel_launch(void* const* d_in, const int* in_sizes, int n_in,
                              void* d_out, int out_size, void* d_ws, size_t ws_size,
                              hipStream_t stream) {
  const int* tokens = (const int*)d_in[0];
  const float* emb = (const float*)d_in[1];
  const float* W1 = (const float*)d_in[2];
  const float* U1 = (const float*)d_in[3];
  const float* b1 = (const float*)d_in[4];
  const float* W2 = (const float*)d_in[5];
  const float* U2 = (const float*)d_in[6];
  const float* b2 = (const float*)d_in[7];
  const float* Wout = (const float*)d_in[8];
  const float* bout = (const float*)d_in[9];
  float* out = (float*)d_out;
  char* ws = (char*)d_ws;

  const size_t oXP = 0;          // 80*1024*128 bf16 = 20971520
  const size_t oW1T = 20971520;  // 2048*128 bf16
  const size_t oU1T = 21495808;  // 2048*512 bf16
  const size_t oW2T = 23592960;
  const size_t oU2T = 25690112;
  const size_t oH1 = 27787264;   // 2 x 1024*512 bf16
  const size_t oH2 = 29884416;
  const size_t oBar = 31981568;  // barrier counter (64B)
  if (ws_size < 36175872) return;

  bf16* XP = (bf16*)(ws + oXP);
  bf16* W1T = (bf16*)(ws + oW1T);
  bf16* U1T = (bf16*)(ws + oU1T);
  bf16* W2T = (bf16*)(ws + oW2T);
  bf16* U2T = (bf16*)(ws + oU2T);
  bf16* H1 = (bf16*)(ws + oH1);
  bf16* H2 = (bf16*)(ws + oH2);
  unsigned* bar = (unsigned*)(ws + oBar);

  hipMemsetAsync(ws + oH1, 0, 1048576, stream);  // H1 buf0
  hipMemsetAsync(ws + oH2, 0, 1048576, stream);  // H2 buf0
  hipMemsetAsync(ws + oBar, 0, 64, stream);      // barrier counter

  embed_kernel<<<40960, 256, 0, stream>>>(tokens, emb, XP);
  transpose_kernel<<<dim3(64, 4), 256, 0, stream>>>(W1, W1T, 100, 128);
  transpose_kernel<<<dim3(64, 16), 256, 0, stream>>>(U1, U1T, 512, 512);
  transpose_kernel<<<dim3(64, 16), 256, 0, stream>>>(W2, W2T, 512, 512);
  transpose_kernel<<<dim3(64, 16), 256, 0, stream>>>(U2, U2T, 512, 512);

  lstm_persist<<<NBLK, 512, 0, stream>>>(XP, W1T, U1T, W2T, U2T, b1, b2, H1, H2, bar);

  // final h2 in buffer (T_&1)==0
  output_kernel<<<256, 256, 0, stream>>>(H2, Wout, bout, out);
}